// Round 7
// baseline (139.492 us; speedup 1.0000x reference)
//
#include <hip/hip_runtime.h>
#include <hip/hip_bf16.h>
#include <math.h>

// FieldTypedProjector: per-token Fourier features -> per-kind 2-layer MLP (exact GELU)
//   out[t] = W2[k]^T gelu(W1[k]^T ff(v_t) + b1[k]) + b2[k] + kind_emb[k]
// R7: persistent fproj. 512 blocks (64/kind, 2/CU), each wave pins its column
// slice of W1+W2 as B-fragments in registers (160 VGPRs) and loops over ~4
// 32-token tiles: steady-state L2 weight traffic -> 0 (was 320 MB/call).
// nt-pair split keeps peak regs ~240 (<256 for 2 waves/SIMD); Hpack double-
// buffered (1 barrier/tile); cos folded into sin via +0.25-rev phase fold.

#define NK 8
#define DM 256
#define TMAX 65536     // N*S = 32*2048
#define NBLK 256       // T/256 histogram/scatter blocks
#define W1PK 16384     // per-kind packed W1 elements (64*256)
#define W2PK 65536     // per-kind packed W2 elements (256*256)
#define LDSTRIDE 262   // prep slab stride

typedef __attribute__((ext_vector_type(8))) short   s16x8;
typedef __attribute__((ext_vector_type(8))) __bf16  bf16x8;
typedef __attribute__((ext_vector_type(4))) float   f32x4;
typedef __attribute__((ext_vector_type(2))) float   f32x2;
typedef __attribute__((ext_vector_type(4))) int     i32x4;

// Static device scratch — rewritten every call (never touches d_ws).
__device__ int   g_counts[NK];
__device__ __align__(16) int g_blkcnt[NBLK][NK];
__device__ int   g_bucket[(size_t)NK * TMAX];
__device__ __align__(16) short g_W1p[(size_t)NK * W1PK];
__device__ __align__(16) short g_W2p[(size_t)NK * W2PK];

static __device__ __forceinline__ short f2bf(float f) {
    __hip_bfloat16 h = __float2bfloat16(f);
    return __builtin_bit_cast(short, h);
}

// round-to-nearest-ish bf16 truncation (<=1 ulp bf16)
static __device__ __forceinline__ short pkbf(float f) {
    unsigned u = __builtin_bit_cast(unsigned, f);
    return (short)((u + 0x8000u) >> 16);
}

static __device__ __forceinline__ f32x4 mfma16(s16x8 a, s16x8 b, f32x4 c) {
    return __builtin_amdgcn_mfma_f32_16x16x32_bf16(
        __builtin_bit_cast(bf16x8, a), __builtin_bit_cast(bf16x8, b), c, 0, 0, 0);
}

// tanh-form GELU: x*sigmoid(1.59577(x+0.044715x^3)); |err| vs exact erf ~3e-4
static __device__ __forceinline__ float gelu_fast(float x) {
    float t1 = x * x;
    float m  = fmaf(0.0713548162726f, t1, 1.59576912161f);
    float z  = m * x;
    float e  = __expf(-z);
    return x * __frcp_rn(1.0f + e);
}

// ---------------- kernel A: weight pack (LDS-staged) + per-block histograms ---
__global__ __launch_bounds__(256) void prep_kernel(const float* __restrict__ W1,
                                                   const float* __restrict__ W2,
                                                   const int* __restrict__ kinds, int T) {
    __shared__ float ld[32 * LDSTRIDE];
    __shared__ int wcnt[4][NK];
    const int tid = threadIdx.x;
    const int bid = blockIdx.x;
    if (bid < 80) {
        const int isW1 = (bid >= 64);
        int kind, kt;
        if (isW1) { kind = (bid - 64) >> 1; kt = (bid - 64) & 1; }
        else      { kind = bid >> 3;        kt = bid & 7; }
        #pragma unroll
        for (int i = 0; i < 8; ++i) {
            int f = tid + i * 256;
            int row = f >> 6, col = (f & 63) * 4;
            int kk = kt * 32 + row;
            f32x4 v = (f32x4){0.f, 0.f, 0.f, 0.f};
            if (isW1) {
                if (kk < 48) v = *(const f32x4*)(W1 + ((size_t)kind * 48 + kk) * DM + col);
            } else {
                v = *(const f32x4*)(W2 + ((size_t)kind * DM + kk) * DM + col);
            }
            float* dst = &ld[row * LDSTRIDE + col];
            *(f32x2*)dst       = (f32x2){v[0], v[1]};
            *(f32x2*)(dst + 2) = (f32x2){v[2], v[3]};
        }
        __syncthreads();
        short* outp = isW1 ? (g_W1p + (size_t)kind * W1PK) : (g_W2p + (size_t)kind * W2PK);
        #pragma unroll
        for (int i = 0; i < 4; ++i) {
            int g = tid + i * 256;
            int ntile = g >> 6, l = g & 63;
            int kk0 = (l >> 4) * 8, n = ntile * 16 + (l & 15);
            s16x8 v;
            #pragma unroll
            for (int j = 0; j < 8; ++j) v[j] = f2bf(ld[(kk0 + j) * LDSTRIDE + n]);
            *(s16x8*)(outp + ((size_t)(kt * 16 + ntile) * 64 + l) * 8) = v;
        }
    } else {
        const int b = bid - 80;
        const int wave = tid >> 6, lane = tid & 63;
        int t = b * 256 + tid;
        int k = (t < T) ? kinds[t] : -1;
        #pragma unroll
        for (int kk = 0; kk < NK; ++kk) {
            unsigned long long m = __ballot(k == kk);
            if (lane == 0) wcnt[wave][kk] = __popcll(m);
        }
        __syncthreads();
        if (tid < NK) {
            int s = 0;
            #pragma unroll
            for (int w = 0; w < 4; ++w) s += wcnt[w][tid];
            g_blkcnt[b][tid] = s;
        }
    }
}

// ---------------- kernel B: two-level scan over block counts + scatter --------
__global__ __launch_bounds__(256) void scatter_kernel(const int* __restrict__ kinds, int T) {
    __shared__ int cnt_s[NBLK * NK];
    __shared__ int chunksum[32][NK];
    __shared__ int chunkpref[32][NK];
    __shared__ int wcnt[4][NK];
    __shared__ int base_s[NK];
    const int tid = threadIdx.x, wave = tid >> 6, lane = tid & 63;
    const int b = blockIdx.x;
    {
        const i32x4* src = (const i32x4*)&g_blkcnt[0][0];
        i32x4* dst = (i32x4*)cnt_s;
        dst[tid]       = src[tid];
        dst[tid + 256] = src[tid + 256];
    }
    int t = b * 256 + tid;
    int k = (t < T) ? kinds[t] : -1;
    int rank = 0;
    #pragma unroll
    for (int kk = 0; kk < NK; ++kk) {
        unsigned long long m = __ballot(k == kk);
        if (lane == 0) wcnt[wave][kk] = __popcll(m);
        if (k == kk) rank = __popcll(m & ((1ull << lane) - 1ull));
    }
    __syncthreads();
    {
        int kk = tid & 7, ch = tid >> 3;
        int s = 0;
        #pragma unroll
        for (int i = 0; i < 8; ++i) s += cnt_s[(ch * 8 + i) * NK + kk];
        chunksum[ch][kk] = s;
    }
    __syncthreads();
    if (tid < NK) {
        int s = 0;
        #pragma unroll
        for (int ch = 0; ch < 32; ++ch) { chunkpref[ch][tid] = s; s += chunksum[ch][tid]; }
        if (b == 0) g_counts[tid] = s;
        int ch = b >> 3;
        int s2 = chunkpref[ch][tid];
        for (int bb = ch * 8; bb < b; ++bb) s2 += cnt_s[bb * NK + tid];
        base_s[tid] = s2;
        int ws = 0;
        #pragma unroll
        for (int w = 0; w < 4; ++w) { int c = wcnt[w][tid]; wcnt[w][tid] = ws; ws += c; }
    }
    __syncthreads();
    if (k >= 0)
        g_bucket[(size_t)k * T + base_s[k] + wcnt[wave][k] + rank] = t;
}

// ---------------- kernel C: persistent fused MLP, weights pinned in registers -
__global__ __launch_bounds__(256, 2) void fproj_gemm(
    const float* __restrict__ values, const float* __restrict__ Bmat,
    const float* __restrict__ kind_emb, const float* __restrict__ b1,
    const float* __restrict__ b2, float* __restrict__ out, int T)
{
    const int k    = blockIdx.x >> 6;      // 64 persistent blocks per kind
    const int slot = blockIdx.x & 63;
    const int cnt  = g_counts[k];
    const int ntiles = (cnt + 31) >> 5;

    const int tid  = threadIdx.x;
    const int wave = tid >> 6;
    const int lane = tid & 63;
    const int quad = lane >> 4;
    const int cl   = lane & 15;

    __shared__ short Hbuf[2][8192];        // double-buffered h 32x256 A-frag order

    // ---- pin this wave's weight slice (cols [wave*64, +64)) in registers
    const s16x8* B1p = (const s16x8*)(g_W1p + (size_t)k * W1PK);
    const s16x8* B2p = (const s16x8*)(g_W2p + (size_t)k * W2PK);
    s16x8 w1f[2][4], w2f[8][4];
    #pragma unroll
    for (int kt = 0; kt < 2; ++kt)
        #pragma unroll
        for (int nt = 0; nt < 4; ++nt) w1f[kt][nt] = B1p[(kt * 16 + wave * 4 + nt) * 64 + lane];
    #pragma unroll
    for (int kt = 0; kt < 8; ++kt)
        #pragma unroll
        for (int nt = 0; nt < 4; ++nt) w2f[kt][nt] = B2p[(kt * 16 + wave * 4 + nt) * 64 + lane];

    // per-column constants, loaded once
    float biasc[4], addc[4];
    #pragma unroll
    for (int nt = 0; nt < 4; ++nt) {
        int c = wave * 64 + nt * 16 + cl;
        biasc[nt] = b1[k * DM + c];
        addc[nt]  = b2[k * DM + c] + kind_emb[k * DM + c];
    }

    const int* buckbase = g_bucket + (size_t)k * T;

    for (int tile = slot; tile < ntiles; tile += 64) {
        const int m0    = tile * 32;
        const int valid = min(32, cnt - m0);
        const int* buck = buckbase + m0;
        short* Hp = Hbuf[(tile >> 6) & 1];

        // ---- Fourier features in A-frag registers (cos = sin with +0.25-rev fold)
        float vm[2];
        vm[0] = (cl < valid)      ? values[buck[cl]]      : 0.0f;
        vm[1] = (16 + cl < valid) ? values[buck[16 + cl]] : 0.0f;
        s16x8 a0[2], a1[2];
        #pragma unroll
        for (int mt = 0; mt < 2; ++mt) {
            float v = vm[mt];
            #pragma unroll
            for (int j = 0; j < 8; ++j) {
                // kt=0: quad 0..2 -> sin band quad*8+j; quad 3 -> cos band j
                int  b0   = (quad == 3) ? j : quad * 8 + j;
                float ph0 = fmaf(v, Bmat[b0], (quad == 3) ? 0.25f : 0.0f);
                a0[mt][j] = pkbf(__builtin_amdgcn_sinf(__builtin_amdgcn_fractf(ph0)));
                // kt=1: quad 0 -> cos band 8+j; quad 1 -> cos band 16+j; quad 2,3 -> 0
                int  b1i  = min(8 * (quad + 1) + j, 23);
                float ph1 = fmaf(v, Bmat[b1i], 0.25f);
                float c1  = __builtin_amdgcn_sinf(__builtin_amdgcn_fractf(ph1));
                a1[mt][j] = pkbf((quad < 2) ? c1 : 0.0f);
            }
        }

        // ---- GEMM1 + GELU -> Hp, split by nt-pairs (caps live acc at 16 regs)
        #pragma unroll
        for (int np = 0; np < 2; ++np) {
            f32x4 acc[2][2];
            #pragma unroll
            for (int mt = 0; mt < 2; ++mt)
                #pragma unroll
                for (int n2 = 0; n2 < 2; ++n2) acc[mt][n2] = (f32x4){0.f, 0.f, 0.f, 0.f};
            #pragma unroll
            for (int kt = 0; kt < 2; ++kt)
                #pragma unroll
                for (int mt = 0; mt < 2; ++mt) {
                    s16x8 a = kt ? a1[mt] : a0[mt];
                    #pragma unroll
                    for (int n2 = 0; n2 < 2; ++n2)
                        acc[mt][n2] = mfma16(a, w1f[kt][np * 2 + n2], acc[mt][n2]);
                }
            #pragma unroll
            for (int n2 = 0; n2 < 2; ++n2) {
                int nt = np * 2 + n2;
                int c  = wave * 64 + nt * 16 + cl;
                int kt2 = c >> 5, q2 = (c >> 3) & 3, j2 = c & 7;
                #pragma unroll
                for (int mt = 0; mt < 2; ++mt) {
                    short* hp = Hp + (kt2 * 2 + mt) * 512 + (q2 << 4) * 8 + j2;
                    #pragma unroll
                    for (int r = 0; r < 4; ++r) {
                        int m = quad * 4 + r;
                        float h = gelu_fast(acc[mt][n2][r] + biasc[nt]);
                        hp[m * 8] = pkbf(h);
                    }
                }
            }
        }
        __syncthreads();

        // ---- GEMM2 + epilogue, split by nt-pairs
        const s16x8* Hpv = (const s16x8*)Hp;
        #pragma unroll
        for (int np = 0; np < 2; ++np) {
            f32x4 acc2[2][2];
            #pragma unroll
            for (int mt = 0; mt < 2; ++mt)
                #pragma unroll
                for (int n2 = 0; n2 < 2; ++n2) acc2[mt][n2] = (f32x4){0.f, 0.f, 0.f, 0.f};
            #pragma unroll
            for (int kt = 0; kt < 8; ++kt) {
                s16x8 am[2];
                #pragma unroll
                for (int mt = 0; mt < 2; ++mt) am[mt] = Hpv[(kt * 2 + mt) * 64 + lane];
                #pragma unroll
                for (int mt = 0; mt < 2; ++mt)
                    #pragma unroll
                    for (int n2 = 0; n2 < 2; ++n2)
                        acc2[mt][n2] = mfma16(am[mt], w2f[kt][np * 2 + n2], acc2[mt][n2]);
            }
            #pragma unroll
            for (int mt = 0; mt < 2; ++mt)
                #pragma unroll
                for (int r = 0; r < 4; ++r) {
                    int row = mt * 16 + quad * 4 + r;
                    if (row < valid) {
                        size_t ro = (size_t)buck[row] * DM;
                        #pragma unroll
                        for (int n2 = 0; n2 < 2; ++n2) {
                            int nt = np * 2 + n2;
                            int c  = wave * 64 + nt * 16 + cl;
                            __builtin_nontemporal_store(acc2[mt][n2][r] + addc[nt],
                                                        out + ro + c);
                        }
                    }
                }
        }
        // no barrier needed here: next iteration writes the other H buffer
    }
}

extern "C" void kernel_launch(void* const* d_in, const int* in_sizes, int n_in,
                              void* d_out, int out_size, void* d_ws, size_t ws_size,
                              hipStream_t stream) {
    const float* values   = (const float*)d_in[0];
    const int*   kinds    = (const int*)  d_in[1];
    const float* Bmat     = (const float*)d_in[2];
    const float* kind_emb = (const float*)d_in[3];
    const float* W1       = (const float*)d_in[4];
    const float* b1       = (const float*)d_in[5];
    const float* W2       = (const float*)d_in[6];
    const float* b2       = (const float*)d_in[7];
    float* out = (float*)d_out;
    const int T = in_sizes[0];   // 65536

    prep_kernel<<<dim3(80 + NBLK), dim3(256), 0, stream>>>(W1, W2, kinds, T);
    scatter_kernel<<<dim3(NBLK), dim3(256), 0, stream>>>(kinds, T);
    fproj_gemm<<<dim3(NK * 64), dim3(256), 0, stream>>>(values, Bmat, kind_emb,
                                                        b1, b2, out, T);
}